// Round 1
// baseline (224.880 us; speedup 1.0000x reference)
//
#include <hip/hip_runtime.h>

#define ROWS 128
#define COLS 117
#define NOUT1 20

// requant: y = x*m (fp32 round), y += off (fp32 round), trunc toward zero to
// int64, arithmetic >> s, clamp [0,255]. Matches jnp reference exactly.
__device__ __forceinline__ float requant(float x, float m, float off, int s) {
  float y = __fmul_rn(x, m);
  y = __fadd_rn(y, off);
  long long yi = (long long)y;   // trunc toward zero, like astype(int64)
  yi >>= s;                      // arithmetic shift
  float r = (float)yi;
  return fminf(fmaxf(r, 0.0f), 255.0f);
}

// Transpose W1 [20,117] -> W1T [117,20] so the 20 weights for a given k are
// contiguous -> uniform s_load_dwordx batches in the main kernel.
__global__ void transpose_w1(const float* __restrict__ W1, float* __restrict__ w1t) {
  for (int idx = threadIdx.x; idx < NOUT1 * COLS; idx += blockDim.x) {
    int o = idx / COLS, k = idx % COLS;
    w1t[k * NOUT1 + o] = W1[idx];
  }
}

// TW=true: W1 is transposed [117,20] (ws path). TW=false: raw [20,117].
template <bool TW>
__global__ __launch_bounds__(128) void fann_kernel(
    const float* __restrict__ X, const float* __restrict__ W1,
    const float* __restrict__ b1, const float* __restrict__ W2,
    const float* __restrict__ b2, float* __restrict__ out) {
  // 128 rows * 117 cols staged in LDS; float4-aligned (128*117*4 = 59904 B,
  // 59904 % 16 == 0, and block base offset 59904*bid is 16B-aligned).
  __shared__ float4 xs4[ROWS * COLS / 4];
  float* xs = (float*)xs4;
  const int t = threadIdx.x;
  const size_t base = (size_t)blockIdx.x * (ROWS * COLS);
  const float4* __restrict__ src = reinterpret_cast<const float4*>(X + base);
  constexpr int NV = ROWS * COLS / 4;       // 3744 float4s
  constexpr int FULL = NV / 128;            // 29 full sweeps
  #pragma unroll
  for (int i = 0; i < FULL; ++i) xs4[t + i * 128] = src[t + i * 128];
  if (t < NV - FULL * 128) xs4[t + FULL * 128] = src[t + FULL * 128];
  __syncthreads();

  // One thread per row: 20 accumulators, x from LDS (stride 117 floats: odd
  // stride -> conflict-free), weights via uniform scalar loads (SGPR).
  float acc[NOUT1];
  #pragma unroll
  for (int o = 0; o < NOUT1; ++o) acc[o] = b1[o];
  const float* xr = xs + t * COLS;
  #pragma unroll 4
  for (int k = 0; k < COLS; ++k) {
    float x = xr[k];
    #pragma unroll
    for (int o = 0; o < NOUT1; ++o) {
      float w = TW ? W1[k * NOUT1 + o] : W1[o * COLS + k];
      acc[o] = fmaf(x, w, acc[o]);
    }
  }

  float s0 = b2[0], s1 = b2[1];
  #pragma unroll
  for (int o = 0; o < NOUT1; ++o) {
    float hq = requant(acc[o], 1565.0f, 16384.0f, 15);
    s0 = fmaf(hq, W2[o], s0);
    s1 = fmaf(hq, W2[NOUT1 + o], s1);
  }
  float r0 = requant(s0, 1342.0f, 16384.0f, 15);
  float r1 = requant(s1, 1342.0f, 16384.0f, 15);
  reinterpret_cast<float2*>(out)[(size_t)blockIdx.x * ROWS + t] =
      make_float2(r0, r1);
}

// Tail for row counts not divisible by ROWS (not hit for B=1048576; kept for
// generality). Scalar loads, one thread per row.
__global__ void fann_tail(const float* __restrict__ X, const float* __restrict__ W1,
                          const float* __restrict__ b1, const float* __restrict__ W2,
                          const float* __restrict__ b2, float* __restrict__ out,
                          int start, int B) {
  int row = start + blockIdx.x * blockDim.x + threadIdx.x;
  if (row >= B) return;
  float acc[NOUT1];
  #pragma unroll
  for (int o = 0; o < NOUT1; ++o) acc[o] = b1[o];
  const float* xr = X + (size_t)row * COLS;
  for (int k = 0; k < COLS; ++k) {
    float x = xr[k];
    #pragma unroll
    for (int o = 0; o < NOUT1; ++o) acc[o] = fmaf(x, W1[o * COLS + k], acc[o]);
  }
  float s0 = b2[0], s1 = b2[1];
  #pragma unroll
  for (int o = 0; o < NOUT1; ++o) {
    float hq = requant(acc[o], 1565.0f, 16384.0f, 15);
    s0 = fmaf(hq, W2[o], s0);
    s1 = fmaf(hq, W2[NOUT1 + o], s1);
  }
  out[(size_t)row * 2 + 0] = requant(s0, 1342.0f, 16384.0f, 15);
  out[(size_t)row * 2 + 1] = requant(s1, 1342.0f, 16384.0f, 15);
}

extern "C" void kernel_launch(void* const* d_in, const int* in_sizes, int n_in,
                              void* d_out, int out_size, void* d_ws, size_t ws_size,
                              hipStream_t stream) {
  const float* X  = (const float*)d_in[0];
  const float* W1 = (const float*)d_in[1];
  const float* b1 = (const float*)d_in[2];
  const float* W2 = (const float*)d_in[3];
  const float* b2 = (const float*)d_in[4];
  float* out = (float*)d_out;
  const int B = in_sizes[0] / COLS;
  const int nblk = B / ROWS;
  const int tail = B - nblk * ROWS;

  const bool useT = ws_size >= (size_t)(COLS * NOUT1 * sizeof(float));
  if (useT) {
    float* w1t = (float*)d_ws;
    transpose_w1<<<1, 256, 0, stream>>>(W1, w1t);
    if (nblk > 0)
      fann_kernel<true><<<nblk, 128, 0, stream>>>(X, w1t, b1, W2, b2, out);
  } else {
    if (nblk > 0)
      fann_kernel<false><<<nblk, 128, 0, stream>>>(X, W1, b1, W2, b2, out);
  }
  if (tail > 0)
    fann_tail<<<(tail + 63) / 64, 64, 0, stream>>>(X, W1, b1, W2, b2, out,
                                                   nblk * ROWS, B);
}

// Round 2
// 108.096 us; speedup vs baseline: 2.0804x; 2.0804x over previous
//
#include <hip/hip_runtime.h>

#define COLS 117
#define NOUT1 20
#define ROWS 64            // rows per block
#define PSTR 21            // padded partial stride (odd -> bank-conflict-free)
#define PFROW (ROWS * PSTR)
#define PFSZ (4 * PFROW)   // 5376 floats, fits in xs (7488 floats)

// requant: y = x*m (fp32 round), y += off (fp32 round), trunc toward zero to
// int64, arithmetic >> s, clamp [0,255]. Matches jnp reference exactly.
__device__ __forceinline__ float requant(float x, float m, float off, int s) {
  float y = __fmul_rn(x, m);
  y = __fadd_rn(y, off);
  long long yi = (long long)y;   // trunc toward zero, like astype(int64)
  yi >>= s;                      // arithmetic shift
  float r = (float)yi;
  return fminf(fmaxf(r, 0.0f), 255.0f);
}

// Transpose W1 [20,117] -> W1T [117,20]: weights for a given k contiguous.
__global__ void transpose_w1(const float* __restrict__ W1, float* __restrict__ w1t) {
  for (int idx = threadIdx.x; idx < NOUT1 * COLS; idx += blockDim.x) {
    int o = idx / COLS, k = idx % COLS;
    w1t[k * NOUT1 + o] = W1[idx];
  }
}

// 256 threads = 4 waves; wave w handles column-quarter w (29/29/29/30 cols)
// of all 64 rows; lane l = row. Weight addresses are wave-uniform -> scalar
// loads. Cross-wave reduction through the (reused) X LDS buffer.
template <bool TW>
__global__ __launch_bounds__(256, 5) void fann_kernel(
    const float* __restrict__ X, const float* __restrict__ W1,
    const float* __restrict__ b1, const float* __restrict__ W2,
    const float* __restrict__ b2, float* __restrict__ out) {
  __shared__ __align__(16) float xs[ROWS * COLS];  // 29,952 B; reused for partials
  float4* xs4 = (float4*)xs;
  const int t = threadIdx.x;
  {
    const float4* __restrict__ src =
        reinterpret_cast<const float4*>(X + (size_t)blockIdx.x * (ROWS * COLS));
    constexpr int NV = ROWS * COLS / 4;  // 1872 float4s (29952 % 16 == 0)
    #pragma unroll
    for (int i = 0; i < NV / 256; ++i)   // 7 full sweeps
      xs4[t + i * 256] = src[t + i * 256];
    if (t < NV - (NV / 256) * 256)       // 80 leftover
      xs4[t + (NV / 256) * 256] = src[t + (NV / 256) * 256];
  }
  __syncthreads();

  const int w = __builtin_amdgcn_readfirstlane(t >> 6);  // wave id in SGPR
  const int l = t & 63;                                  // row within tile
  const int k0 = w * 29;
  const int kn = (w == 3) ? 30 : 29;   // wave-uniform trip count

  float acc[NOUT1];
  #pragma unroll
  for (int o = 0; o < NOUT1; ++o) acc[o] = 0.0f;
  const float* xr = xs + l * COLS + k0;  // stride 117 (odd) -> 2-way = free

  if (TW) {
    const float4* __restrict__ w4 =
        reinterpret_cast<const float4*>(W1) + (size_t)k0 * (NOUT1 / 4);
    for (int kk = 0; kk < kn; ++kk) {
      float x = xr[kk];
      #pragma unroll
      for (int j = 0; j < 5; ++j) {
        float4 wv = w4[kk * 5 + j];   // uniform address -> s_load
        acc[4 * j + 0] = fmaf(x, wv.x, acc[4 * j + 0]);
        acc[4 * j + 1] = fmaf(x, wv.y, acc[4 * j + 1]);
        acc[4 * j + 2] = fmaf(x, wv.z, acc[4 * j + 2]);
        acc[4 * j + 3] = fmaf(x, wv.w, acc[4 * j + 3]);
      }
    }
  } else {
    for (int kk = 0; kk < kn; ++kk) {
      float x = xr[kk];
      #pragma unroll
      for (int o = 0; o < NOUT1; ++o)
        acc[o] = fmaf(x, W1[o * COLS + k0 + kk], acc[o]);
    }
  }

  __syncthreads();  // all waves done READING xs -> safe to overwrite
  {
    float* pw = xs + w * PFROW + l * PSTR;
    #pragma unroll
    for (int o = 0; o < NOUT1; ++o) pw[o] = acc[o];
  }
  __syncthreads();

  // Stage 2: wave w reduces output-group o = 5w..5w+4 for all rows, applies
  // requant, and accumulates its partial of the 2-wide layer 2.
  float* sp0 = xs + PFSZ;        // [4][65] floats (odd stride)
  float* sp1 = sp0 + 4 * 65;     // 5376 + 520 = 5896 <= 7488 floats
  {
    float s0 = 0.0f, s1 = 0.0f;
    #pragma unroll
    for (int j = 0; j < 5; ++j) {
      const int o = w * 5 + j;
      float h = xs[0 * PFROW + l * PSTR + o] + xs[1 * PFROW + l * PSTR + o] +
                xs[2 * PFROW + l * PSTR + o] + xs[3 * PFROW + l * PSTR + o];
      h += b1[o];
      float hq = requant(h, 1565.0f, 16384.0f, 15);
      s0 = fmaf(hq, W2[o], s0);
      s1 = fmaf(hq, W2[NOUT1 + o], s1);
    }
    sp0[w * 65 + l] = s0;
    sp1[w * 65 + l] = s1;
  }
  __syncthreads();

  if (t < ROWS) {
    float s0 = sp0[t] + sp0[65 + t] + sp0[130 + t] + sp0[195 + t] + b2[0];
    float s1 = sp1[t] + sp1[65 + t] + sp1[130 + t] + sp1[195 + t] + b2[1];
    float2 r;
    r.x = requant(s0, 1342.0f, 16384.0f, 15);
    r.y = requant(s1, 1342.0f, 16384.0f, 15);
    reinterpret_cast<float2*>(out)[(size_t)blockIdx.x * ROWS + t] = r;
  }
}

// Tail for row counts not divisible by ROWS (not hit for B=1048576).
__global__ void fann_tail(const float* __restrict__ X, const float* __restrict__ W1,
                          const float* __restrict__ b1, const float* __restrict__ W2,
                          const float* __restrict__ b2, float* __restrict__ out,
                          int start, int B) {
  int row = start + blockIdx.x * blockDim.x + threadIdx.x;
  if (row >= B) return;
  float acc[NOUT1];
  #pragma unroll
  for (int o = 0; o < NOUT1; ++o) acc[o] = b1[o];
  const float* xr = X + (size_t)row * COLS;
  for (int k = 0; k < COLS; ++k) {
    float x = xr[k];
    #pragma unroll
    for (int o = 0; o < NOUT1; ++o) acc[o] = fmaf(x, W1[o * COLS + k], acc[o]);
  }
  float s0 = b2[0], s1 = b2[1];
  #pragma unroll
  for (int o = 0; o < NOUT1; ++o) {
    float hq = requant(acc[o], 1565.0f, 16384.0f, 15);
    s0 = fmaf(hq, W2[o], s0);
    s1 = fmaf(hq, W2[NOUT1 + o], s1);
  }
  out[(size_t)row * 2 + 0] = requant(s0, 1342.0f, 16384.0f, 15);
  out[(size_t)row * 2 + 1] = requant(s1, 1342.0f, 16384.0f, 15);
}

extern "C" void kernel_launch(void* const* d_in, const int* in_sizes, int n_in,
                              void* d_out, int out_size, void* d_ws, size_t ws_size,
                              hipStream_t stream) {
  const float* X  = (const float*)d_in[0];
  const float* W1 = (const float*)d_in[1];
  const float* b1 = (const float*)d_in[2];
  const float* W2 = (const float*)d_in[3];
  const float* b2 = (const float*)d_in[4];
  float* out = (float*)d_out;
  const int B = in_sizes[0] / COLS;
  const int nblk = B / ROWS;
  const int tail = B - nblk * ROWS;

  const bool useT = ws_size >= (size_t)(COLS * NOUT1 * sizeof(float));
  if (useT) {
    float* w1t = (float*)d_ws;
    transpose_w1<<<1, 256, 0, stream>>>(W1, w1t);
    if (nblk > 0)
      fann_kernel<true><<<nblk, 256, 0, stream>>>(X, w1t, b1, W2, b2, out);
  } else {
    if (nblk > 0)
      fann_kernel<false><<<nblk, 256, 0, stream>>>(X, W1, b1, W2, b2, out);
  }
  if (tail > 0)
    fann_tail<<<(tail + 63) / 64, 64, 0, stream>>>(X, W1, b1, W2, b2, out,
                                                   nblk * ROWS, B);
}